// Round 15
// baseline (367.223 us; speedup 1.0000x reference)
//
#include <hip/hip_runtime.h>
#include <hip/hip_bf16.h>
#include <hip/hip_cooperative_groups.h>
#include <math.h>

namespace cg = cooperative_groups;

// Problem constants (match reference)
#define NN   20000
#define EE   320000
#define OBS  256
#define HID  256
#define EMB  128
#define MLPH 512
#define ACT  64

#define SCAN_NB ((NN + 255) / 256)   // 79 scan blocks
#define COOP_NB ((EE / 4 + 255) / 256)  // 313 blocks (covers edges, nodes, zeroing)

using short8 = __attribute__((ext_vector_type(8))) short;
using f32x4  = __attribute__((ext_vector_type(4))) float;

__device__ __forceinline__ unsigned short f2b(float v) {
    __hip_bfloat16 b = __float2bfloat16(v);
    return *reinterpret_cast<unsigned short*>(&b);
}
__device__ __forceinline__ float b2f(unsigned short u) {
    return __uint_as_float(((unsigned int)u) << 16);
}

// ---------------- fused prep: x->bf16, 6 weight transposes ----------------
#define PREP_CONV 2500
#define PREP_WT   (PREP_CONV + 512)

__global__ __launch_bounds__(256) void prep_all(
    const float* __restrict__ x, unsigned short* __restrict__ xb,
    const float* W0, const float* W1, const float* W2,
    const float* W3, const float* W4, const float* W5,
    unsigned short* T0, unsigned short* T1, unsigned short* T2,
    unsigned short* T3, unsigned short* T4, unsigned short* T5)
{
    __shared__ float t[32][33];
    const int b   = blockIdx.x;
    const int tid = threadIdx.x;

    if (b < PREP_CONV) {
        const int i = (b * 256 + tid) * 8;   // NN*OBS = 5,120,000 = 2500*256*8 exactly
        float4 a = *reinterpret_cast<const float4*>(&x[i]);
        float4 c = *reinterpret_cast<const float4*>(&x[i + 4]);
        short8 o;
        o[0] = (short)f2b(a.x); o[1] = (short)f2b(a.y); o[2] = (short)f2b(a.z); o[3] = (short)f2b(a.w);
        o[4] = (short)f2b(c.x); o[5] = (short)f2b(c.y); o[6] = (short)f2b(c.z); o[7] = (short)f2b(c.w);
        *reinterpret_cast<short8*>(&xb[i]) = o;
        return;
    }
    {
        int local = b - PREP_CONV;
        const float* W; unsigned short* T; int K, N;
        if      (local < 64)  { W = W0; T = T0; K = OBS;  N = HID; }
        else if (local < 128) { W = W1; T = T1; K = HID;  N = HID;  local -= 64; }
        else if (local < 160) { W = W2; T = T2; K = HID;  N = EMB;  local -= 128; }
        else if (local < 224) { W = W3; T = T3; K = EMB;  N = MLPH; local -= 160; }
        else if (local < 480) { W = W4; T = T4; K = MLPH; N = MLPH; local -= 224; }
        else                  { W = W5; T = T5; K = MLPH; N = ACT;  local -= 480; }
        const int tk = K / 32;
        const int k0 = (local % tk) * 32;
        const int n0 = (local / tk) * 32;
        const int tx = tid & 31, ty = tid >> 5;   // 32 x 8
        for (int i = 0; i < 32; i += 8)
            t[ty + i][tx] = W[(size_t)(k0 + ty + i) * N + (n0 + tx)];
        __syncthreads();
        for (int i = 0; i < 32; i += 8)
            T[(size_t)(n0 + ty + i) * K + (k0 + tx)] = f2b(t[tx][ty + i]);
    }
}

// ---------------- cooperative CSR build: zero -> histogram -> partials -> scan -> fill ----------------
__global__ __launch_bounds__(256) void csr_build_coop(
    const int* __restrict__ src, const int* __restrict__ dst,
    int* __restrict__ cnt2, int* __restrict__ row_start, int* __restrict__ cursor,
    int* __restrict__ partial, int* __restrict__ csr_src,
    float* __restrict__ dinv_in, float* __restrict__ dinv_out)
{
    cg::grid_group grid = cg::this_grid();
    __shared__ int ws[4];
    __shared__ int praw[128], pscan[128], wsum[4];

    const int tid  = threadIdx.x;
    const int gtid = blockIdx.x * 256 + tid;
    const int lane = tid & 63, wv = tid >> 6;
    int* cnt_in  = cnt2;
    int* cnt_out = cnt2 + NN;

    // P0: zero histograms (2*NN = 40000 <= 80128 threads)
    if (gtid < 2 * NN) cnt2[gtid] = 0;
    grid.sync();

    // P1: edge histogram (int4)
    if (gtid * 4 < EE) {
        int4 s = *reinterpret_cast<const int4*>(&src[gtid * 4]);
        int4 d = *reinterpret_cast<const int4*>(&dst[gtid * 4]);
        atomicAdd(&cnt_out[s.x], 1); atomicAdd(&cnt_out[s.y], 1);
        atomicAdd(&cnt_out[s.z], 1); atomicAdd(&cnt_out[s.w], 1);
        atomicAdd(&cnt_in[d.x], 1);  atomicAdd(&cnt_in[d.y], 1);
        atomicAdd(&cnt_in[d.z], 1);  atomicAdd(&cnt_in[d.w], 1);
    }
    grid.sync();

    // P2: per-block partial sums + dinv
    if (blockIdx.x < SCAN_NB) {
        const int i = blockIdx.x * 256 + tid;
        int v = 0;
        if (i < NN) {
            v = cnt_in[i];
            dinv_in[i]  = rsqrtf((float)(v + 1));
            dinv_out[i] = rsqrtf((float)(cnt_out[i] + 1));
        }
        int s = v;
#pragma unroll
        for (int o = 32; o >= 1; o >>= 1) s += __shfl_xor(s, o);
        if (lane == 0) ws[wv] = s;
        __syncthreads();
        if (tid == 0) partial[blockIdx.x] = ws[0] + ws[1] + ws[2] + ws[3];
    }
    grid.sync();

    // P3: scan of partials (redundant per block) + block-local scan -> row_start, cursor
    if (blockIdx.x < SCAN_NB) {
        if (tid < 128) {
            int v = (tid < SCAN_NB) ? partial[tid] : 0;
            praw[tid] = v; pscan[tid] = v;
        }
        __syncthreads();
        for (int off = 1; off < 128; off <<= 1) {
            int u = (tid < 128 && tid >= off) ? pscan[tid - off] : 0;
            __syncthreads();
            if (tid < 128) pscan[tid] += u;
            __syncthreads();
        }
        const int bexcl = pscan[blockIdx.x] - praw[blockIdx.x];

        const int i = blockIdx.x * 256 + tid;
        int v = (i < NN) ? cnt_in[i] : 0;
        int x = v;
#pragma unroll
        for (int o = 1; o < 64; o <<= 1) {
            int u = __shfl_up(x, o);
            if (lane >= o) x += u;
        }
        if (lane == 63) wsum[wv] = x;
        __syncthreads();
        int wadd = 0;
        for (int w = 0; w < wv; ++w) wadd += wsum[w];
        const int excl = x - v + wadd + bexcl;
        if (i < NN) { row_start[i] = excl; cursor[i] = excl; }
        if (blockIdx.x == 0 && tid == 0) row_start[NN] = EE;
    }
    grid.sync();

    // P4: fill CSR (int4)
    if (gtid * 4 < EE) {
        int4 s = *reinterpret_cast<const int4*>(&src[gtid * 4]);
        int4 d = *reinterpret_cast<const int4*>(&dst[gtid * 4]);
        csr_src[atomicAdd(&cursor[d.x], 1)] = s.x;
        csr_src[atomicAdd(&cursor[d.y], 1)] = s.y;
        csr_src[atomicAdd(&cursor[d.z], 1)] = s.z;
        csr_src[atomicAdd(&cursor[d.w], 1)] = s.w;
    }
}

// ---------------- bf16 MFMA GEMM: 2-buffer depth-1 pipeline (TLP-first) ----------------
// C[M x N] = act( rs[r]*(X@W) + bias[c] ),  W given as WT[N][K].
// BM x BN tile, BK=32, 4 waves (2x2), per-wave (BM/2)x(BN/2).
// LDS per buffer: A [BM][32] + B [BN][32], 64B rows; chunk swizzle period-16
// (physical = logical ^ (row&3) ^ ((row>>2)&3)) on global source + ds_read addr.
// 2 buffers; counted vmcnt keeps next-tile loads in flight across the barrier.
// MW=6 waves/EU -> 6 blocks/CU (VGPR cap 85; kernel uses ~76). Grid: 1-D
// col-fastest + bijective XCD chunk.
template <int BM, int BN, int MW>
__global__ __launch_bounds__(256, MW) void gemm_bf16(
    const unsigned short* __restrict__ X, const unsigned short* __restrict__ WT,
    int M, int K, int N, int ncb,
    const float* __restrict__ rs, const float* __restrict__ bias, int act,
    unsigned short* __restrict__ Ob, float* __restrict__ Of)
{
    constexpr int AREG = BM * 32;
    constexpr int BREG = BN * 32;
    constexpr int BUF  = AREG + BREG;
    constexpr int WR   = BM / 2;
    constexpr int WC   = BN / 2;
    constexpr int MF   = BM / 32;
    constexpr int NF   = BN / 32;
    constexpr int AL   = BM / 64;
    constexpr int BL   = BN / 64;
    constexpr int LPT  = AL + BL;

    __shared__ __align__(16) unsigned short lds[2 * BUF];

    const int tid  = threadIdx.x;
    const int lane = tid & 63;
    const int wv   = tid >> 6;
    const int wm   = wv >> 1;
    const int wn   = wv & 1;

    // bijective XCD chunking, col-fastest decode
    const int nwg = gridDim.x;
    const int qq  = nwg >> 3, rr8 = nwg & 7;
    const int xcd = blockIdx.x & 7, jj = blockIdx.x >> 3;
    const int lid = (xcd < rr8 ? xcd * (qq + 1) : rr8 * (qq + 1) + (xcd - rr8) * qq) + jj;
    const int row0 = (lid / ncb) * BM;
    const int col0 = (lid % ncb) * BN;

    // staging: 4 consecutive lanes cover one row's 64B (coalesced), chunk pre-swizzled
    const int strow  = lane >> 2;                                      // 0..15
    const int schunk = (lane & 3) ^ (strow & 3) ^ ((strow >> 2) & 3);

    const int l15 = lane & 15;
    const int kc  = lane >> 4;                                         // logical k-chunk
    const int pc  = kc ^ (l15 & 3) ^ ((l15 >> 2) & 3);                 // physical chunk

    f32x4 acc[MF][NF] = {};

    auto stage = [&](int buf, int k0) {
#pragma unroll
        for (int rr = 0; rr < AL; ++rr) {
            int r  = rr * 64 + wv * 16 + strow;
            int gr = min(row0 + r, M - 1);
            const unsigned short* srcA = X + (size_t)gr * K + k0 + schunk * 8;
            unsigned short* dstA = &lds[buf * BUF + rr * 2048 + wv * 512];
            __builtin_amdgcn_global_load_lds(
                (const __attribute__((address_space(1))) void*)srcA,
                (__attribute__((address_space(3))) void*)dstA, 16, 0, 0);
        }
#pragma unroll
        for (int rr = 0; rr < BL; ++rr) {
            int r  = rr * 64 + wv * 16 + strow;
            int gn = min(col0 + r, N - 1);
            const unsigned short* srcB = WT + (size_t)gn * K + k0 + schunk * 8;
            unsigned short* dstB = &lds[buf * BUF + AREG + rr * 2048 + wv * 512];
            __builtin_amdgcn_global_load_lds(
                (const __attribute__((address_space(1))) void*)srcB,
                (__attribute__((address_space(3))) void*)dstB, 16, 0, 0);
        }
    };

    const int nt = K >> 5;
    stage(0, 0);
    int cur = 0;
    for (int t = 0; t < nt; ++t) {
        if (t + 1 < nt) {
            stage(cur ^ 1, (t + 1) << 5);
            if constexpr (LPT == 2)      asm volatile("s_waitcnt vmcnt(2)" ::: "memory");
            else if constexpr (LPT == 3) asm volatile("s_waitcnt vmcnt(3)" ::: "memory");
            else if constexpr (LPT == 4) asm volatile("s_waitcnt vmcnt(4)" ::: "memory");
            else                         asm volatile("s_waitcnt vmcnt(6)" ::: "memory");
        } else {
            asm volatile("s_waitcnt vmcnt(0)" ::: "memory");
        }
        __builtin_amdgcn_s_barrier();
        __builtin_amdgcn_sched_barrier(0);

        short8 af[MF], bfr[NF];
#pragma unroll
        for (int mi = 0; mi < MF; ++mi) {
            int fr = wm * WR + mi * 16 + l15;
            af[mi] = *reinterpret_cast<const short8*>(&lds[cur * BUF + fr * 32 + pc * 8]);
        }
#pragma unroll
        for (int ni = 0; ni < NF; ++ni) {
            int fn = wn * WC + ni * 16 + l15;
            bfr[ni] = *reinterpret_cast<const short8*>(&lds[cur * BUF + AREG + fn * 32 + pc * 8]);
        }
#pragma unroll
        for (int mi = 0; mi < MF; ++mi)
#pragma unroll
            for (int ni = 0; ni < NF; ++ni)
                acc[mi][ni] = __builtin_amdgcn_mfma_f32_16x16x32_bf16(af[mi], bfr[ni], acc[mi][ni], 0, 0, 0);

        __builtin_amdgcn_s_barrier();
        cur ^= 1;
    }

    if (act == 3) {
        // fused softmax epilogue (N == 64: all cols live in wn==0 fragments, BN==128)
        if (wn == 1) return;
#pragma unroll
        for (int mi = 0; mi < MF; ++mi) {
#pragma unroll
            for (int q = 0; q < 4; ++q) {
                int r = row0 + wm * WR + mi * 16 + (lane >> 4) * 4 + q;
                if (r >= M) continue;
                float v[NF];
                float mx = -1e30f;
#pragma unroll
                for (int ni = 0; ni < NF; ++ni) {
                    v[ni] = acc[mi][ni][q] + bias[ni * 16 + l15];
                    mx = fmaxf(mx, v[ni]);
                }
#pragma unroll
                for (int o = 8; o >= 1; o >>= 1) mx = fmaxf(mx, __shfl_xor(mx, o));
                float s = 0.0f;
#pragma unroll
                for (int ni = 0; ni < NF; ++ni) { v[ni] = expf(v[ni] - mx); s += v[ni]; }
#pragma unroll
                for (int o = 8; o >= 1; o >>= 1) s += __shfl_xor(s, o);
                float inv = 1.0f / s;
#pragma unroll
                for (int ni = 0; ni < NF; ++ni)
                    Of[(size_t)r * 64 + ni * 16 + l15] = v[ni] * inv;
            }
        }
        return;
    }

#pragma unroll
    for (int mi = 0; mi < MF; ++mi) {
#pragma unroll
        for (int q = 0; q < 4; ++q) {
            int r = row0 + wm * WR + mi * 16 + (lane >> 4) * 4 + q;
            if (r >= M) continue;
            float rsv = rs ? rs[r] : 1.0f;
#pragma unroll
            for (int ni = 0; ni < NF; ++ni) {
                int c = col0 + wn * WC + ni * 16 + l15;
                if (c >= N) continue;
                float v = acc[mi][ni][q] * rsv;
                if (bias) v += bias[c];
                if (act == 1) v = fmaxf(v, 0.0f);
                size_t idx = (size_t)r * N + c;
                if (Ob) Ob[idx] = f2b(v);
                if (Of) Of[idx] = v;
            }
        }
    }
}

// ---------------- CSR gather: group-parallel edges, 16B/lane ----------------
// F=256: 2 groups of 32 lanes (2 edges in parallel); F=128: 4 groups of 16 lanes.
// Each lane owns 8 features (16B). Groups combined at end via shfl_xor.
template <int F, int ACTMODE, bool OUTF32>
__global__ __launch_bounds__(256) void gather_bf16(
    const unsigned short* __restrict__ A, unsigned short* __restrict__ Yb,
    float* __restrict__ Yf,
    const int* __restrict__ row_start, const int* __restrict__ csr_src,
    const float* __restrict__ dinv_in, const float* __restrict__ bias)
{
    constexpr int P   = (F == 256) ? 2 : 4;   // parallel edge groups
    constexpr int LPG = 64 / P;               // lanes per group
    const int wave = threadIdx.x >> 6;
    const int lane = threadIdx.x & 63;
    const int node = blockIdx.x * 4 + wave;
    if (node >= NN) return;
    const int g  = lane / LPG;
    const int li = lane % LPG;
    const int f0 = li * 8;

    float acc[8] = {};
    if (g == 0) {
        short8 u = *reinterpret_cast<const short8*>(A + (size_t)node * F + f0);
#pragma unroll
        for (int j = 0; j < 8; ++j) acc[j] = b2f((unsigned short)u[j]);
    }

    const int lo = row_start[node];
    const int hi = row_start[node + 1];
    int e = lo + g;
    for (; e + P < hi; e += 2 * P) {
        int s0 = csr_src[e];
        int s1 = csr_src[e + P];
        short8 u0 = *reinterpret_cast<const short8*>(A + (size_t)s0 * F + f0);
        short8 u1 = *reinterpret_cast<const short8*>(A + (size_t)s1 * F + f0);
#pragma unroll
        for (int j = 0; j < 8; ++j)
            acc[j] += b2f((unsigned short)u0[j]) + b2f((unsigned short)u1[j]);
    }
    if (e < hi) {
        int s0 = csr_src[e];
        short8 u0 = *reinterpret_cast<const short8*>(A + (size_t)s0 * F + f0);
#pragma unroll
        for (int j = 0; j < 8; ++j) acc[j] += b2f((unsigned short)u0[j]);
    }

    // combine groups
#pragma unroll
    for (int j = 0; j < 8; ++j) {
        if (P == 4) acc[j] += __shfl_xor(acc[j], 16);
        acc[j] += __shfl_xor(acc[j], 32);
    }

    const float di = dinv_in[node];
#pragma unroll
    for (int j = 0; j < 8; ++j) {
        float xv = acc[j] * di + bias[f0 + j];
        if (ACTMODE == 1) xv = fmaxf(xv, 0.0f);
        else              xv = 1.0f / (1.0f + expf(-xv)) + 1e-8f;
        acc[j] = xv;
    }
    if (g == 0) {
        if (Yb) {
            short8 o;
#pragma unroll
            for (int j = 0; j < 8; ++j) o[j] = (short)f2b(acc[j]);
            *reinterpret_cast<short8*>(Yb + (size_t)node * F + f0) = o;
        }
        if (OUTF32) {
            float* yf = Yf + (size_t)node * F + f0;
            *reinterpret_cast<float4*>(yf)     = make_float4(acc[0], acc[1], acc[2], acc[3]);
            *reinterpret_cast<float4*>(yf + 4) = make_float4(acc[4], acc[5], acc[6], acc[7]);
        }
    }
}

// ---------------- launcher ----------------
extern "C" void kernel_launch(void* const* d_in, const int* in_sizes, int n_in,
                              void* d_out, int out_size, void* d_ws, size_t ws_size,
                              hipStream_t stream)
{
    const float* x   = (const float*)d_in[0];
    const int*   src = (const int*)d_in[1];
    const int*   dst = (const int*)d_in[2];
    const float* Wg1 = (const float*)d_in[3];
    const float* bg1 = (const float*)d_in[4];
    const float* Wg2 = (const float*)d_in[5];
    const float* bg2 = (const float*)d_in[6];
    const float* Wg3 = (const float*)d_in[7];
    const float* bg3 = (const float*)d_in[8];
    const float* W1  = (const float*)d_in[9];
    const float* b1  = (const float*)d_in[10];
    const float* W2  = (const float*)d_in[11];
    const float* b2  = (const float*)d_in[12];
    const float* W3  = (const float*)d_in[13];
    const float* b3  = (const float*)d_in[14];

    float* out  = (float*)d_out;
    float* prob = out;                     // [N x 64]
    float* gnn  = out + (size_t)NN * ACT;  // [N x 128]

    char* p = (char*)d_ws;
    auto alloc = [&](size_t bytes) { char* r = p; p += (bytes + 255) & ~(size_t)255; return r; };
    float*          dinv_out = (float*)alloc((size_t)NN * 4);
    float*          dinv_in  = (float*)alloc((size_t)NN * 4);
    int*            cnt2     = (int*)alloc((size_t)2 * NN * 4);   // [cnt_in | cnt_out]
    int*            row_st   = (int*)alloc((size_t)(NN + 1) * 4);
    int*            cursor   = (int*)alloc((size_t)NN * 4);
    int*            partial  = (int*)alloc((size_t)SCAN_NB * 4);
    int*            csr_src  = (int*)alloc((size_t)EE * 4);
    unsigned short* xb       = (unsigned short*)alloc((size_t)NN * OBS * 2);
    unsigned short* WT1      = (unsigned short*)alloc((size_t)HID * OBS * 2);
    unsigned short* WT2      = (unsigned short*)alloc((size_t)HID * HID * 2);
    unsigned short* WT3      = (unsigned short*)alloc((size_t)EMB * HID * 2);
    unsigned short* WTm1     = (unsigned short*)alloc((size_t)MLPH * EMB * 2);
    unsigned short* WTm2     = (unsigned short*)alloc((size_t)MLPH * MLPH * 2);
    unsigned short* WTm3     = (unsigned short*)alloc((size_t)ACT * MLPH * 2);
    unsigned short* actA     = (unsigned short*)alloc((size_t)NN * 512 * 2);
    unsigned short* actB     = (unsigned short*)alloc((size_t)NN * 512 * 2);

    // --- cooperative CSR build (zero + histogram + scan + fill, one dispatch) ---
    {
        void* args[] = { (void*)&src, (void*)&dst, (void*)&cnt2, (void*)&row_st,
                         (void*)&cursor, (void*)&partial, (void*)&csr_src,
                         (void*)&dinv_in, (void*)&dinv_out };
        hipLaunchCooperativeKernel((void*)csr_build_coop, dim3(COOP_NB), dim3(256),
                                   args, 0, stream);
    }

    // --- fused prep: conversions + weight transposes ---
    prep_all<<<PREP_WT, 256, 0, stream>>>(x, xb, Wg1, Wg2, Wg3, W1, W2, W3,
                                          WT1, WT2, WT3, WTm1, WTm2, WTm3);

    const int rb64 = (NN + 63) / 64;      // 313
    const int gb = (NN + 3) / 4;

    // --- GCN layer 1 ---
    gemm_bf16<64, 128, 6><<<rb64 * 2, 256, 0, stream>>>(xb, WT1, NN, OBS, HID, 2, dinv_out, nullptr, 0, actA, nullptr);
    gather_bf16<HID, 1, false><<<gb, 256, 0, stream>>>(actA, actB, nullptr, row_st, csr_src, dinv_in, bg1);

    // --- GCN layer 2 ---
    gemm_bf16<64, 128, 6><<<rb64 * 2, 256, 0, stream>>>(actB, WT2, NN, HID, HID, 2, dinv_out, nullptr, 0, actA, nullptr);
    gather_bf16<HID, 1, false><<<gb, 256, 0, stream>>>(actA, actB, nullptr, row_st, csr_src, dinv_in, bg2);

    // --- GCN layer 3 -> gnn (f32, in d_out) + bf16 copy for MLP ---
    gemm_bf16<64, 64, 6><<<rb64 * 2, 256, 0, stream>>>(actB, WT3, NN, HID, EMB, 2, dinv_out, nullptr, 0, actA, nullptr);
    gather_bf16<EMB, 2, true><<<gb, 256, 0, stream>>>(actA, actB, gnn, row_st, csr_src, dinv_in, bg3);

    // --- MLP (softmax fused into last GEMM) ---
    gemm_bf16<64, 128, 6><<<rb64 * 4, 256, 0, stream>>>(actB, WTm1, NN, EMB, MLPH, 4, nullptr, b1, 1, actA, nullptr);
    gemm_bf16<64, 128, 6><<<rb64 * 4, 256, 0, stream>>>(actA, WTm2, NN, MLPH, MLPH, 4, nullptr, b2, 1, actB, nullptr);
    gemm_bf16<64, 128, 6><<<rb64, 256, 0, stream>>>(actB, WTm3, NN, MLPH, ACT, 1, nullptr, b3, 3, nullptr, prob);
}

// Round 16
// 231.162 us; speedup vs baseline: 1.5886x; 1.5886x over previous
//
#include <hip/hip_runtime.h>
#include <hip/hip_bf16.h>
#include <math.h>

// Problem constants (match reference)
#define NN   20000
#define EE   320000
#define OBS  256
#define HID  256
#define EMB  128
#define MLPH 512
#define ACT  64

#define SCAN_NB ((NN + 255) / 256)   // 79 scan blocks

using short8 = __attribute__((ext_vector_type(8))) short;
using f32x4  = __attribute__((ext_vector_type(4))) float;

__device__ __forceinline__ unsigned short f2b(float v) {
    __hip_bfloat16 b = __float2bfloat16(v);
    return *reinterpret_cast<unsigned short*>(&b);
}
__device__ __forceinline__ float b2f(unsigned short u) {
    return __uint_as_float(((unsigned int)u) << 16);
}

// ---------------- fused prep: x->bf16, 6 weight transposes, zero histograms ----------------
#define PREP_CONV 2500
#define PREP_WT   (PREP_CONV + 512)
#define PREP_ZERO (PREP_WT + 40)

__global__ __launch_bounds__(256) void prep_all(
    const float* __restrict__ x, unsigned short* __restrict__ xb,
    const float* W0, const float* W1, const float* W2,
    const float* W3, const float* W4, const float* W5,
    unsigned short* T0, unsigned short* T1, unsigned short* T2,
    unsigned short* T3, unsigned short* T4, unsigned short* T5,
    int* __restrict__ cnt2)
{
    __shared__ float t[32][33];
    const int b   = blockIdx.x;
    const int tid = threadIdx.x;

    if (b < PREP_CONV) {
        const int i = (b * 256 + tid) * 8;   // NN*OBS = 5,120,000 = 2500*256*8 exactly
        float4 a = *reinterpret_cast<const float4*>(&x[i]);
        float4 c = *reinterpret_cast<const float4*>(&x[i + 4]);
        short8 o;
        o[0] = (short)f2b(a.x); o[1] = (short)f2b(a.y); o[2] = (short)f2b(a.z); o[3] = (short)f2b(a.w);
        o[4] = (short)f2b(c.x); o[5] = (short)f2b(c.y); o[6] = (short)f2b(c.z); o[7] = (short)f2b(c.w);
        *reinterpret_cast<short8*>(&xb[i]) = o;
        return;
    }
    if (b < PREP_WT) {
        int local = b - PREP_CONV;
        const float* W; unsigned short* T; int K, N;
        if      (local < 64)  { W = W0; T = T0; K = OBS;  N = HID; }
        else if (local < 128) { W = W1; T = T1; K = HID;  N = HID;  local -= 64; }
        else if (local < 160) { W = W2; T = T2; K = HID;  N = EMB;  local -= 128; }
        else if (local < 224) { W = W3; T = T3; K = EMB;  N = MLPH; local -= 160; }
        else if (local < 480) { W = W4; T = T4; K = MLPH; N = MLPH; local -= 224; }
        else                  { W = W5; T = T5; K = MLPH; N = ACT;  local -= 480; }
        const int tk = K / 32;
        const int k0 = (local % tk) * 32;
        const int n0 = (local / tk) * 32;
        const int tx = tid & 31, ty = tid >> 5;   // 32 x 8
        for (int i = 0; i < 32; i += 8)
            t[ty + i][tx] = W[(size_t)(k0 + ty + i) * N + (n0 + tx)];
        __syncthreads();
        for (int i = 0; i < 32; i += 8)
            T[(size_t)(n0 + ty + i) * K + (k0 + tx)] = f2b(t[tx][ty + i]);
        return;
    }
    {
        const int i = ((b - PREP_WT) * 256 + tid) * 4;
        if (i + 3 < 2 * NN) {
            *reinterpret_cast<int4*>(&cnt2[i]) = make_int4(0, 0, 0, 0);
        } else {
            for (int j = i; j < 2 * NN; ++j) cnt2[j] = 0;
        }
    }
}

// ---------------- degree / CSR kernels (int4-vectorized over edges) ----------------
__global__ __launch_bounds__(256) void edge_deg(const int* __restrict__ src, const int* __restrict__ dst,
                                                int* __restrict__ cnt_out, int* __restrict__ cnt_in) {
    const int i4 = blockIdx.x * 256 + threadIdx.x;
    if (i4 * 4 >= EE) return;
    int4 s = *reinterpret_cast<const int4*>(&src[i4 * 4]);
    int4 d = *reinterpret_cast<const int4*>(&dst[i4 * 4]);
    atomicAdd(&cnt_out[s.x], 1); atomicAdd(&cnt_out[s.y], 1);
    atomicAdd(&cnt_out[s.z], 1); atomicAdd(&cnt_out[s.w], 1);
    atomicAdd(&cnt_in[d.x], 1);  atomicAdd(&cnt_in[d.y], 1);
    atomicAdd(&cnt_in[d.z], 1);  atomicAdd(&cnt_in[d.w], 1);
}

__global__ __launch_bounds__(256) void csr_partials(
    const int* __restrict__ cnt_in, const int* __restrict__ cnt_out,
    int* __restrict__ partial, float* __restrict__ dinv_in, float* __restrict__ dinv_out)
{
    const int i = blockIdx.x * 256 + threadIdx.x;
    int v = 0;
    if (i < NN) {
        v = cnt_in[i];
        dinv_in[i]  = rsqrtf((float)(v + 1));
        dinv_out[i] = rsqrtf((float)(cnt_out[i] + 1));
    }
    int s = v;
#pragma unroll
    for (int o = 32; o >= 1; o >>= 1) s += __shfl_xor(s, o);
    __shared__ int ws[4];
    const int lane = threadIdx.x & 63, wv = threadIdx.x >> 6;
    if (lane == 0) ws[wv] = s;
    __syncthreads();
    if (threadIdx.x == 0) partial[blockIdx.x] = ws[0] + ws[1] + ws[2] + ws[3];
}

__global__ __launch_bounds__(256) void csr_scan_write(
    const int* __restrict__ cnt_in, const int* __restrict__ partial,
    int* __restrict__ row_start, int* __restrict__ cursor)
{
    __shared__ int praw[128], pscan[128];
    const int b   = blockIdx.x;
    const int tid = threadIdx.x;
    if (tid < 128) {
        int v = (tid < SCAN_NB) ? partial[tid] : 0;
        praw[tid] = v; pscan[tid] = v;
    }
    __syncthreads();
    for (int off = 1; off < 128; off <<= 1) {
        int u = (tid < 128 && tid >= off) ? pscan[tid - off] : 0;
        __syncthreads();
        if (tid < 128) pscan[tid] += u;
        __syncthreads();
    }
    const int bexcl = pscan[b] - praw[b];

    const int i = b * 256 + tid;
    const int lane = tid & 63, wv = tid >> 6;
    int v = (i < NN) ? cnt_in[i] : 0;
    int x = v;
#pragma unroll
    for (int o = 1; o < 64; o <<= 1) {
        int u = __shfl_up(x, o);
        if (lane >= o) x += u;
    }
    __shared__ int wsum[4];
    if (lane == 63) wsum[wv] = x;
    __syncthreads();
    int wadd = 0;
    for (int w = 0; w < wv; ++w) wadd += wsum[w];
    const int excl = x - v + wadd + bexcl;
    if (i < NN) { row_start[i] = excl; cursor[i] = excl; }
    if (b == 0 && tid == 0) row_start[NN] = EE;
}

__global__ __launch_bounds__(256) void fill_csr(const int* __restrict__ src, const int* __restrict__ dst,
                                                int* __restrict__ cursor, int* __restrict__ csr_src)
{
    const int i4 = blockIdx.x * 256 + threadIdx.x;
    if (i4 * 4 >= EE) return;
    int4 s = *reinterpret_cast<const int4*>(&src[i4 * 4]);
    int4 d = *reinterpret_cast<const int4*>(&dst[i4 * 4]);
    csr_src[atomicAdd(&cursor[d.x], 1)] = s.x;
    csr_src[atomicAdd(&cursor[d.y], 1)] = s.y;
    csr_src[atomicAdd(&cursor[d.z], 1)] = s.z;
    csr_src[atomicAdd(&cursor[d.w], 1)] = s.w;
}

// ---------------- bf16 MFMA GEMM: 2-buffer depth-1 pipeline (TLP-first) ----------------
// C[M x N] = act( rs[r]*(X@W) + bias[c] ),  W given as WT[N][K].
// BM x BN tile, BK=32, 4 waves (2x2), per-wave (BM/2)x(BN/2).
// LDS per buffer: A [BM][32] + B [BN][32], 64B rows; chunk swizzle period-16
// (physical = logical ^ (row&3) ^ ((row>>2)&3)) on global source + ds_read addr.
// 2 buffers; counted vmcnt keeps next-tile loads in flight across the barrier.
// MW=6 waves/EU -> 6 blocks/CU (VGPR cap 85; kernel uses ~76). Grid: 1-D
// col-fastest + bijective XCD chunk.
template <int BM, int BN, int MW>
__global__ __launch_bounds__(256, MW) void gemm_bf16(
    const unsigned short* __restrict__ X, const unsigned short* __restrict__ WT,
    int M, int K, int N, int ncb,
    const float* __restrict__ rs, const float* __restrict__ bias, int act,
    unsigned short* __restrict__ Ob, float* __restrict__ Of)
{
    constexpr int AREG = BM * 32;
    constexpr int BREG = BN * 32;
    constexpr int BUF  = AREG + BREG;
    constexpr int WR   = BM / 2;
    constexpr int WC   = BN / 2;
    constexpr int MF   = BM / 32;
    constexpr int NF   = BN / 32;
    constexpr int AL   = BM / 64;
    constexpr int BL   = BN / 64;
    constexpr int LPT  = AL + BL;

    __shared__ __align__(16) unsigned short lds[2 * BUF];

    const int tid  = threadIdx.x;
    const int lane = tid & 63;
    const int wv   = tid >> 6;
    const int wm   = wv >> 1;
    const int wn   = wv & 1;

    // bijective XCD chunking, col-fastest decode
    const int nwg = gridDim.x;
    const int qq  = nwg >> 3, rr8 = nwg & 7;
    const int xcd = blockIdx.x & 7, jj = blockIdx.x >> 3;
    const int lid = (xcd < rr8 ? xcd * (qq + 1) : rr8 * (qq + 1) + (xcd - rr8) * qq) + jj;
    const int row0 = (lid / ncb) * BM;
    const int col0 = (lid % ncb) * BN;

    // staging: 4 consecutive lanes cover one row's 64B (coalesced), chunk pre-swizzled
    const int strow  = lane >> 2;                                      // 0..15
    const int schunk = (lane & 3) ^ (strow & 3) ^ ((strow >> 2) & 3);

    const int l15 = lane & 15;
    const int kc  = lane >> 4;                                         // logical k-chunk
    const int pc  = kc ^ (l15 & 3) ^ ((l15 >> 2) & 3);                 // physical chunk

    f32x4 acc[MF][NF] = {};

    auto stage = [&](int buf, int k0) {
#pragma unroll
        for (int rr = 0; rr < AL; ++rr) {
            int r  = rr * 64 + wv * 16 + strow;
            int gr = min(row0 + r, M - 1);
            const unsigned short* srcA = X + (size_t)gr * K + k0 + schunk * 8;
            unsigned short* dstA = &lds[buf * BUF + rr * 2048 + wv * 512];
            __builtin_amdgcn_global_load_lds(
                (const __attribute__((address_space(1))) void*)srcA,
                (__attribute__((address_space(3))) void*)dstA, 16, 0, 0);
        }
#pragma unroll
        for (int rr = 0; rr < BL; ++rr) {
            int r  = rr * 64 + wv * 16 + strow;
            int gn = min(col0 + r, N - 1);
            const unsigned short* srcB = WT + (size_t)gn * K + k0 + schunk * 8;
            unsigned short* dstB = &lds[buf * BUF + AREG + rr * 2048 + wv * 512];
            __builtin_amdgcn_global_load_lds(
                (const __attribute__((address_space(1))) void*)srcB,
                (__attribute__((address_space(3))) void*)dstB, 16, 0, 0);
        }
    };

    const int nt = K >> 5;
    stage(0, 0);
    int cur = 0;
    for (int t = 0; t < nt; ++t) {
        if (t + 1 < nt) {
            stage(cur ^ 1, (t + 1) << 5);
            if constexpr (LPT == 2)      asm volatile("s_waitcnt vmcnt(2)" ::: "memory");
            else if constexpr (LPT == 3) asm volatile("s_waitcnt vmcnt(3)" ::: "memory");
            else if constexpr (LPT == 4) asm volatile("s_waitcnt vmcnt(4)" ::: "memory");
            else                         asm volatile("s_waitcnt vmcnt(6)" ::: "memory");
        } else {
            asm volatile("s_waitcnt vmcnt(0)" ::: "memory");
        }
        __builtin_amdgcn_s_barrier();
        __builtin_amdgcn_sched_barrier(0);

        short8 af[MF], bfr[NF];
#pragma unroll
        for (int mi = 0; mi < MF; ++mi) {
            int fr = wm * WR + mi * 16 + l15;
            af[mi] = *reinterpret_cast<const short8*>(&lds[cur * BUF + fr * 32 + pc * 8]);
        }
#pragma unroll
        for (int ni = 0; ni < NF; ++ni) {
            int fn = wn * WC + ni * 16 + l15;
            bfr[ni] = *reinterpret_cast<const short8*>(&lds[cur * BUF + AREG + fn * 32 + pc * 8]);
        }
#pragma unroll
        for (int mi = 0; mi < MF; ++mi)
#pragma unroll
            for (int ni = 0; ni < NF; ++ni)
                acc[mi][ni] = __builtin_amdgcn_mfma_f32_16x16x32_bf16(af[mi], bfr[ni], acc[mi][ni], 0, 0, 0);

        __builtin_amdgcn_s_barrier();
        cur ^= 1;
    }

    if (act == 3) {
        // fused softmax epilogue (N == 64: all cols live in wn==0 fragments, BN==128)
        if (wn == 1) return;
#pragma unroll
        for (int mi = 0; mi < MF; ++mi) {
#pragma unroll
            for (int q = 0; q < 4; ++q) {
                int r = row0 + wm * WR + mi * 16 + (lane >> 4) * 4 + q;
                if (r >= M) continue;
                float v[NF];
                float mx = -1e30f;
#pragma unroll
                for (int ni = 0; ni < NF; ++ni) {
                    v[ni] = acc[mi][ni][q] + bias[ni * 16 + l15];
                    mx = fmaxf(mx, v[ni]);
                }
#pragma unroll
                for (int o = 8; o >= 1; o >>= 1) mx = fmaxf(mx, __shfl_xor(mx, o));
                float s = 0.0f;
#pragma unroll
                for (int ni = 0; ni < NF; ++ni) { v[ni] = expf(v[ni] - mx); s += v[ni]; }
#pragma unroll
                for (int o = 8; o >= 1; o >>= 1) s += __shfl_xor(s, o);
                float inv = 1.0f / s;
#pragma unroll
                for (int ni = 0; ni < NF; ++ni)
                    Of[(size_t)r * 64 + ni * 16 + l15] = v[ni] * inv;
            }
        }
        return;
    }

#pragma unroll
    for (int mi = 0; mi < MF; ++mi) {
#pragma unroll
        for (int q = 0; q < 4; ++q) {
            int r = row0 + wm * WR + mi * 16 + (lane >> 4) * 4 + q;
            if (r >= M) continue;
            float rsv = rs ? rs[r] : 1.0f;
#pragma unroll
            for (int ni = 0; ni < NF; ++ni) {
                int c = col0 + wn * WC + ni * 16 + l15;
                if (c >= N) continue;
                float v = acc[mi][ni][q] * rsv;
                if (bias) v += bias[c];
                if (act == 1) v = fmaxf(v, 0.0f);
                size_t idx = (size_t)r * N + c;
                if (Ob) Ob[idx] = f2b(v);
                if (Of) Of[idx] = v;
            }
        }
    }
}

// ---------------- CSR gather: group-parallel edges, 16B/lane ----------------
// F=256: 2 groups of 32 lanes (2 edges in parallel); F=128: 4 groups of 16 lanes.
// Each lane owns 8 features (16B). Groups combined at end via shfl_xor.
template <int F, int ACTMODE, bool OUTF32>
__global__ __launch_bounds__(256) void gather_bf16(
    const unsigned short* __restrict__ A, unsigned short* __restrict__ Yb,
    float* __restrict__ Yf,
    const int* __restrict__ row_start, const int* __restrict__ csr_src,
    const float* __restrict__ dinv_in, const float* __restrict__ bias)
{
    constexpr int P   = (F == 256) ? 2 : 4;   // parallel edge groups
    constexpr int LPG = 64 / P;               // lanes per group
    const int wave = threadIdx.x >> 6;
    const int lane = threadIdx.x & 63;
    const int node = blockIdx.x * 4 + wave;
    if (node >= NN) return;
    const int g  = lane / LPG;
    const int li = lane % LPG;
    const int f0 = li * 8;

    float acc[8] = {};
    if (g == 0) {
        short8 u = *reinterpret_cast<const short8*>(A + (size_t)node * F + f0);
#pragma unroll
        for (int j = 0; j < 8; ++j) acc[j] = b2f((unsigned short)u[j]);
    }

    const int lo = row_start[node];
    const int hi = row_start[node + 1];
    int e = lo + g;
    for (; e + P < hi; e += 2 * P) {
        int s0 = csr_src[e];
        int s1 = csr_src[e + P];
        short8 u0 = *reinterpret_cast<const short8*>(A + (size_t)s0 * F + f0);
        short8 u1 = *reinterpret_cast<const short8*>(A + (size_t)s1 * F + f0);
#pragma unroll
        for (int j = 0; j < 8; ++j)
            acc[j] += b2f((unsigned short)u0[j]) + b2f((unsigned short)u1[j]);
    }
    if (e < hi) {
        int s0 = csr_src[e];
        short8 u0 = *reinterpret_cast<const short8*>(A + (size_t)s0 * F + f0);
#pragma unroll
        for (int j = 0; j < 8; ++j) acc[j] += b2f((unsigned short)u0[j]);
    }

    // combine groups
#pragma unroll
    for (int j = 0; j < 8; ++j) {
        if (P == 4) acc[j] += __shfl_xor(acc[j], 16);
        acc[j] += __shfl_xor(acc[j], 32);
    }

    const float di = dinv_in[node];
#pragma unroll
    for (int j = 0; j < 8; ++j) {
        float xv = acc[j] * di + bias[f0 + j];
        if (ACTMODE == 1) xv = fmaxf(xv, 0.0f);
        else              xv = 1.0f / (1.0f + expf(-xv)) + 1e-8f;
        acc[j] = xv;
    }
    if (g == 0) {
        if (Yb) {
            short8 o;
#pragma unroll
            for (int j = 0; j < 8; ++j) o[j] = (short)f2b(acc[j]);
            *reinterpret_cast<short8*>(Yb + (size_t)node * F + f0) = o;
        }
        if (OUTF32) {
            float* yf = Yf + (size_t)node * F + f0;
            *reinterpret_cast<float4*>(yf)     = make_float4(acc[0], acc[1], acc[2], acc[3]);
            *reinterpret_cast<float4*>(yf + 4) = make_float4(acc[4], acc[5], acc[6], acc[7]);
        }
    }
}

// ---------------- launcher ----------------
extern "C" void kernel_launch(void* const* d_in, const int* in_sizes, int n_in,
                              void* d_out, int out_size, void* d_ws, size_t ws_size,
                              hipStream_t stream)
{
    const float* x   = (const float*)d_in[0];
    const int*   src = (const int*)d_in[1];
    const int*   dst = (const int*)d_in[2];
    const float* Wg1 = (const float*)d_in[3];
    const float* bg1 = (const float*)d_in[4];
    const float* Wg2 = (const float*)d_in[5];
    const float* bg2 = (const float*)d_in[6];
    const float* Wg3 = (const float*)d_in[7];
    const float* bg3 = (const float*)d_in[8];
    const float* W1  = (const float*)d_in[9];
    const float* b1  = (const float*)d_in[10];
    const float* W2  = (const float*)d_in[11];
    const float* b2  = (const float*)d_in[12];
    const float* W3  = (const float*)d_in[13];
    const float* b3  = (const float*)d_in[14];

    float* out  = (float*)d_out;
    float* prob = out;                     // [N x 64]
    float* gnn  = out + (size_t)NN * ACT;  // [N x 128]

    char* p = (char*)d_ws;
    auto alloc = [&](size_t bytes) { char* r = p; p += (bytes + 255) & ~(size_t)255; return r; };
    float*          dinv_out = (float*)alloc((size_t)NN * 4);
    float*          dinv_in  = (float*)alloc((size_t)NN * 4);
    int*            cnt2     = (int*)alloc((size_t)2 * NN * 4);   // [cnt_in | cnt_out]
    int*            row_st   = (int*)alloc((size_t)(NN + 1) * 4);
    int*            cursor   = (int*)alloc((size_t)NN * 4);
    int*            partial  = (int*)alloc((size_t)SCAN_NB * 4);
    int*            csr_src  = (int*)alloc((size_t)EE * 4);
    unsigned short* xb       = (unsigned short*)alloc((size_t)NN * OBS * 2);
    unsigned short* WT1      = (unsigned short*)alloc((size_t)HID * OBS * 2);
    unsigned short* WT2      = (unsigned short*)alloc((size_t)HID * HID * 2);
    unsigned short* WT3      = (unsigned short*)alloc((size_t)EMB * HID * 2);
    unsigned short* WTm1     = (unsigned short*)alloc((size_t)MLPH * EMB * 2);
    unsigned short* WTm2     = (unsigned short*)alloc((size_t)MLPH * MLPH * 2);
    unsigned short* WTm3     = (unsigned short*)alloc((size_t)ACT * MLPH * 2);
    unsigned short* actA     = (unsigned short*)alloc((size_t)NN * 512 * 2);
    unsigned short* actB     = (unsigned short*)alloc((size_t)NN * 512 * 2);

    int* cnt_in  = cnt2;
    int* cnt_out = cnt2 + NN;

    // --- fused prep: conversions + weight transposes + histogram zeroing ---
    prep_all<<<PREP_ZERO, 256, 0, stream>>>(x, xb, Wg1, Wg2, Wg3, W1, W2, W3,
                                            WT1, WT2, WT3, WTm1, WTm2, WTm3, cnt2);

    // --- degrees + CSR (parallel scan) ---
    const int eb = (EE / 4 + 255) / 256;   // 313 edge blocks
    edge_deg<<<eb, 256, 0, stream>>>(src, dst, cnt_out, cnt_in);
    csr_partials<<<SCAN_NB, 256, 0, stream>>>(cnt_in, cnt_out, partial, dinv_in, dinv_out);
    csr_scan_write<<<SCAN_NB, 256, 0, stream>>>(cnt_in, partial, row_st, cursor);
    fill_csr<<<eb, 256, 0, stream>>>(src, dst, cursor, csr_src);

    const int rb64 = (NN + 63) / 64;      // 313
    const int gb = (NN + 3) / 4;

    // --- GCN layer 1 ---
    gemm_bf16<64, 128, 6><<<rb64 * 2, 256, 0, stream>>>(xb, WT1, NN, OBS, HID, 2, dinv_out, nullptr, 0, actA, nullptr);
    gather_bf16<HID, 1, false><<<gb, 256, 0, stream>>>(actA, actB, nullptr, row_st, csr_src, dinv_in, bg1);

    // --- GCN layer 2 ---
    gemm_bf16<64, 128, 6><<<rb64 * 2, 256, 0, stream>>>(actB, WT2, NN, HID, HID, 2, dinv_out, nullptr, 0, actA, nullptr);
    gather_bf16<HID, 1, false><<<gb, 256, 0, stream>>>(actA, actB, nullptr, row_st, csr_src, dinv_in, bg2);

    // --- GCN layer 3 -> gnn (f32, in d_out) + bf16 copy for MLP ---
    gemm_bf16<64, 64, 6><<<rb64 * 2, 256, 0, stream>>>(actB, WT3, NN, HID, EMB, 2, dinv_out, nullptr, 0, actA, nullptr);
    gather_bf16<EMB, 2, true><<<gb, 256, 0, stream>>>(actA, actB, gnn, row_st, csr_src, dinv_in, bg3);

    // --- MLP (softmax fused into last GEMM) ---
    gemm_bf16<64, 128, 6><<<rb64 * 4, 256, 0, stream>>>(actB, WTm1, NN, EMB, MLPH, 4, nullptr, b1, 1, actA, nullptr);
    gemm_bf16<64, 128, 6><<<rb64 * 4, 256, 0, stream>>>(actA, WTm2, NN, MLPH, MLPH, 4, nullptr, b2, 1, actB, nullptr);
    gemm_bf16<64, 128, 6><<<rb64, 256, 0, stream>>>(actB, WTm3, NN, MLPH, ACT, 1, nullptr, b3, 3, nullptr, prob);
}

// Round 17
// 229.961 us; speedup vs baseline: 1.5969x; 1.0052x over previous
//
#include <hip/hip_runtime.h>
#include <hip/hip_bf16.h>
#include <math.h>

// Problem constants (match reference)
#define NN   20000
#define EE   320000
#define OBS  256
#define HID  256
#define EMB  128
#define MLPH 512
#define ACT  64

#define SCAN_NB ((NN + 255) / 256)   // 79 scan blocks

using short8 = __attribute__((ext_vector_type(8))) short;
using f32x4  = __attribute__((ext_vector_type(4))) float;

__device__ __forceinline__ unsigned short f2b(float v) {
    __hip_bfloat16 b = __float2bfloat16(v);
    return *reinterpret_cast<unsigned short*>(&b);
}
__device__ __forceinline__ float b2f(unsigned short u) {
    return __uint_as_float(((unsigned int)u) << 16);
}

// ---------------- fused prep: x->bf16, 6 weight transposes, zero histograms ----------------
#define PREP_CONV 2500
#define PREP_WT   (PREP_CONV + 512)
#define PREP_ZERO (PREP_WT + 40)

__global__ __launch_bounds__(256) void prep_all(
    const float* __restrict__ x, unsigned short* __restrict__ xb,
    const float* W0, const float* W1, const float* W2,
    const float* W3, const float* W4, const float* W5,
    unsigned short* T0, unsigned short* T1, unsigned short* T2,
    unsigned short* T3, unsigned short* T4, unsigned short* T5,
    int* __restrict__ cnt2)
{
    __shared__ float t[32][33];
    const int b   = blockIdx.x;
    const int tid = threadIdx.x;

    if (b < PREP_CONV) {
        const int i = (b * 256 + tid) * 8;   // NN*OBS = 5,120,000 = 2500*256*8 exactly
        float4 a = *reinterpret_cast<const float4*>(&x[i]);
        float4 c = *reinterpret_cast<const float4*>(&x[i + 4]);
        short8 o;
        o[0] = (short)f2b(a.x); o[1] = (short)f2b(a.y); o[2] = (short)f2b(a.z); o[3] = (short)f2b(a.w);
        o[4] = (short)f2b(c.x); o[5] = (short)f2b(c.y); o[6] = (short)f2b(c.z); o[7] = (short)f2b(c.w);
        *reinterpret_cast<short8*>(&xb[i]) = o;
        return;
    }
    if (b < PREP_WT) {
        int local = b - PREP_CONV;
        const float* W; unsigned short* T; int K, N;
        if      (local < 64)  { W = W0; T = T0; K = OBS;  N = HID; }
        else if (local < 128) { W = W1; T = T1; K = HID;  N = HID;  local -= 64; }
        else if (local < 160) { W = W2; T = T2; K = HID;  N = EMB;  local -= 128; }
        else if (local < 224) { W = W3; T = T3; K = EMB;  N = MLPH; local -= 160; }
        else if (local < 480) { W = W4; T = T4; K = MLPH; N = MLPH; local -= 224; }
        else                  { W = W5; T = T5; K = MLPH; N = ACT;  local -= 480; }
        const int tk = K / 32;
        const int k0 = (local % tk) * 32;
        const int n0 = (local / tk) * 32;
        const int tx = tid & 31, ty = tid >> 5;   // 32 x 8
        for (int i = 0; i < 32; i += 8)
            t[ty + i][tx] = W[(size_t)(k0 + ty + i) * N + (n0 + tx)];
        __syncthreads();
        for (int i = 0; i < 32; i += 8)
            T[(size_t)(n0 + ty + i) * K + (k0 + tx)] = f2b(t[tx][ty + i]);
        return;
    }
    {
        const int i = ((b - PREP_WT) * 256 + tid) * 4;
        if (i + 3 < 2 * NN) {
            *reinterpret_cast<int4*>(&cnt2[i]) = make_int4(0, 0, 0, 0);
        } else {
            for (int j = i; j < 2 * NN; ++j) cnt2[j] = 0;
        }
    }
}

// ---------------- degree / CSR kernels (int4-vectorized over edges) ----------------
__global__ __launch_bounds__(256) void edge_deg(const int* __restrict__ src, const int* __restrict__ dst,
                                                int* __restrict__ cnt_out, int* __restrict__ cnt_in) {
    const int i4 = blockIdx.x * 256 + threadIdx.x;
    if (i4 * 4 >= EE) return;
    int4 s = *reinterpret_cast<const int4*>(&src[i4 * 4]);
    int4 d = *reinterpret_cast<const int4*>(&dst[i4 * 4]);
    atomicAdd(&cnt_out[s.x], 1); atomicAdd(&cnt_out[s.y], 1);
    atomicAdd(&cnt_out[s.z], 1); atomicAdd(&cnt_out[s.w], 1);
    atomicAdd(&cnt_in[d.x], 1);  atomicAdd(&cnt_in[d.y], 1);
    atomicAdd(&cnt_in[d.z], 1);  atomicAdd(&cnt_in[d.w], 1);
}

__global__ __launch_bounds__(256) void csr_partials(
    const int* __restrict__ cnt_in, const int* __restrict__ cnt_out,
    int* __restrict__ partial, float* __restrict__ dinv_in, float* __restrict__ dinv_out)
{
    const int i = blockIdx.x * 256 + threadIdx.x;
    int v = 0;
    if (i < NN) {
        v = cnt_in[i];
        dinv_in[i]  = rsqrtf((float)(v + 1));
        dinv_out[i] = rsqrtf((float)(cnt_out[i] + 1));
    }
    int s = v;
#pragma unroll
    for (int o = 32; o >= 1; o >>= 1) s += __shfl_xor(s, o);
    __shared__ int ws[4];
    const int lane = threadIdx.x & 63, wv = threadIdx.x >> 6;
    if (lane == 0) ws[wv] = s;
    __syncthreads();
    if (threadIdx.x == 0) partial[blockIdx.x] = ws[0] + ws[1] + ws[2] + ws[3];
}

__global__ __launch_bounds__(256) void csr_scan_write(
    const int* __restrict__ cnt_in, const int* __restrict__ partial,
    int* __restrict__ row_start, int* __restrict__ cursor)
{
    __shared__ int praw[128], pscan[128];
    const int b   = blockIdx.x;
    const int tid = threadIdx.x;
    if (tid < 128) {
        int v = (tid < SCAN_NB) ? partial[tid] : 0;
        praw[tid] = v; pscan[tid] = v;
    }
    __syncthreads();
    for (int off = 1; off < 128; off <<= 1) {
        int u = (tid < 128 && tid >= off) ? pscan[tid - off] : 0;
        __syncthreads();
        if (tid < 128) pscan[tid] += u;
        __syncthreads();
    }
    const int bexcl = pscan[b] - praw[b];

    const int i = b * 256 + tid;
    const int lane = tid & 63, wv = tid >> 6;
    int v = (i < NN) ? cnt_in[i] : 0;
    int x = v;
#pragma unroll
    for (int o = 1; o < 64; o <<= 1) {
        int u = __shfl_up(x, o);
        if (lane >= o) x += u;
    }
    __shared__ int wsum[4];
    if (lane == 63) wsum[wv] = x;
    __syncthreads();
    int wadd = 0;
    for (int w = 0; w < wv; ++w) wadd += wsum[w];
    const int excl = x - v + wadd + bexcl;
    if (i < NN) { row_start[i] = excl; cursor[i] = excl; }
    if (b == 0 && tid == 0) row_start[NN] = EE;
}

__global__ __launch_bounds__(256) void fill_csr(const int* __restrict__ src, const int* __restrict__ dst,
                                                int* __restrict__ cursor, int* __restrict__ csr_src)
{
    const int i4 = blockIdx.x * 256 + threadIdx.x;
    if (i4 * 4 >= EE) return;
    int4 s = *reinterpret_cast<const int4*>(&src[i4 * 4]);
    int4 d = *reinterpret_cast<const int4*>(&dst[i4 * 4]);
    csr_src[atomicAdd(&cursor[d.x], 1)] = s.x;
    csr_src[atomicAdd(&cursor[d.y], 1)] = s.y;
    csr_src[atomicAdd(&cursor[d.z], 1)] = s.z;
    csr_src[atomicAdd(&cursor[d.w], 1)] = s.w;
}

// ---------------- bf16 MFMA GEMM: 2-buffer depth-1 pipeline (TLP-first) ----------------
// C[M x N] = act( rs[r]*(X@W) + bias[c] ),  W given as WT[N][K].
// BM x BN tile, BK=32, 4 waves (2x2), per-wave (BM/2)x(BN/2).
// LDS per buffer: A [BM][32] + B [BN][32], 64B rows; chunk swizzle period-16
// (physical = logical ^ (row&3) ^ ((row>>2)&3)) on global source + ds_read addr.
// 2 buffers; counted vmcnt keeps next-tile loads in flight across the barrier.
// MW=6 waves/EU -> 6 blocks/CU. Grid: 1-D col-fastest + bijective XCD chunk.
// act==3 (softmax, N==64): BN==64 path does cross-wave LDS softmax;
// BN==128 legacy path kept under constexpr.
template <int BM, int BN, int MW>
__global__ __launch_bounds__(256, MW) void gemm_bf16(
    const unsigned short* __restrict__ X, const unsigned short* __restrict__ WT,
    int M, int K, int N, int ncb,
    const float* __restrict__ rs, const float* __restrict__ bias, int act,
    unsigned short* __restrict__ Ob, float* __restrict__ Of)
{
    constexpr int AREG = BM * 32;
    constexpr int BREG = BN * 32;
    constexpr int BUF  = AREG + BREG;
    constexpr int WR   = BM / 2;
    constexpr int WC   = BN / 2;
    constexpr int MF   = BM / 32;
    constexpr int NF   = BN / 32;
    constexpr int AL   = BM / 64;
    constexpr int BL   = BN / 64;
    constexpr int LPT  = AL + BL;

    __shared__ __align__(16) unsigned short lds[2 * BUF];

    const int tid  = threadIdx.x;
    const int lane = tid & 63;
    const int wv   = tid >> 6;
    const int wm   = wv >> 1;
    const int wn   = wv & 1;

    // bijective XCD chunking, col-fastest decode
    const int nwg = gridDim.x;
    const int qq  = nwg >> 3, rr8 = nwg & 7;
    const int xcd = blockIdx.x & 7, jj = blockIdx.x >> 3;
    const int lid = (xcd < rr8 ? xcd * (qq + 1) : rr8 * (qq + 1) + (xcd - rr8) * qq) + jj;
    const int row0 = (lid / ncb) * BM;
    const int col0 = (lid % ncb) * BN;

    // staging: 4 consecutive lanes cover one row's 64B (coalesced), chunk pre-swizzled
    const int strow  = lane >> 2;                                      // 0..15
    const int schunk = (lane & 3) ^ (strow & 3) ^ ((strow >> 2) & 3);

    const int l15 = lane & 15;
    const int kc  = lane >> 4;                                         // logical k-chunk
    const int pc  = kc ^ (l15 & 3) ^ ((l15 >> 2) & 3);                 // physical chunk

    f32x4 acc[MF][NF] = {};

    auto stage = [&](int buf, int k0) {
#pragma unroll
        for (int rr = 0; rr < AL; ++rr) {
            int r  = rr * 64 + wv * 16 + strow;
            int gr = min(row0 + r, M - 1);
            const unsigned short* srcA = X + (size_t)gr * K + k0 + schunk * 8;
            unsigned short* dstA = &lds[buf * BUF + rr * 2048 + wv * 512];
            __builtin_amdgcn_global_load_lds(
                (const __attribute__((address_space(1))) void*)srcA,
                (__attribute__((address_space(3))) void*)dstA, 16, 0, 0);
        }
#pragma unroll
        for (int rr = 0; rr < BL; ++rr) {
            int r  = rr * 64 + wv * 16 + strow;
            int gn = min(col0 + r, N - 1);
            const unsigned short* srcB = WT + (size_t)gn * K + k0 + schunk * 8;
            unsigned short* dstB = &lds[buf * BUF + AREG + rr * 2048 + wv * 512];
            __builtin_amdgcn_global_load_lds(
                (const __attribute__((address_space(1))) void*)srcB,
                (__attribute__((address_space(3))) void*)dstB, 16, 0, 0);
        }
    };

    const int nt = K >> 5;
    stage(0, 0);
    int cur = 0;
    for (int t = 0; t < nt; ++t) {
        if (t + 1 < nt) {
            stage(cur ^ 1, (t + 1) << 5);
            if constexpr (LPT == 2)      asm volatile("s_waitcnt vmcnt(2)" ::: "memory");
            else if constexpr (LPT == 3) asm volatile("s_waitcnt vmcnt(3)" ::: "memory");
            else if constexpr (LPT == 4) asm volatile("s_waitcnt vmcnt(4)" ::: "memory");
            else                         asm volatile("s_waitcnt vmcnt(6)" ::: "memory");
        } else {
            asm volatile("s_waitcnt vmcnt(0)" ::: "memory");
        }
        __builtin_amdgcn_s_barrier();
        __builtin_amdgcn_sched_barrier(0);

        short8 af[MF], bfr[NF];
#pragma unroll
        for (int mi = 0; mi < MF; ++mi) {
            int fr = wm * WR + mi * 16 + l15;
            af[mi] = *reinterpret_cast<const short8*>(&lds[cur * BUF + fr * 32 + pc * 8]);
        }
#pragma unroll
        for (int ni = 0; ni < NF; ++ni) {
            int fn = wn * WC + ni * 16 + l15;
            bfr[ni] = *reinterpret_cast<const short8*>(&lds[cur * BUF + AREG + fn * 32 + pc * 8]);
        }
#pragma unroll
        for (int mi = 0; mi < MF; ++mi)
#pragma unroll
            for (int ni = 0; ni < NF; ++ni)
                acc[mi][ni] = __builtin_amdgcn_mfma_f32_16x16x32_bf16(af[mi], bfr[ni], acc[mi][ni], 0, 0, 0);

        __builtin_amdgcn_s_barrier();
        cur ^= 1;
    }

    if (act == 3) {
        if constexpr (BN == 64) {
            // cross-wave softmax over 64 cols: wave wn owns cols wn*32..wn*32+31.
            // Exchange per-row max/sum through (now-dead) staging LDS.
            float* smax = (float*)lds;         // [64][2]
            float* ssum = smax + 128;          // [64][2]
            const int hi16 = lane >> 4;
            float vvv[MF][NF][4];
            float rr_[MF][4];

            __syncthreads();   // staging LDS now safe to reuse
#pragma unroll
            for (int mi = 0; mi < MF; ++mi)
#pragma unroll
                for (int q = 0; q < 4; ++q) {
                    float m = -1e30f;
#pragma unroll
                    for (int ni = 0; ni < NF; ++ni) {
                        float v = acc[mi][ni][q] + bias[wn * 32 + ni * 16 + l15];
                        vvv[mi][ni][q] = v;
                        m = fmaxf(m, v);
                    }
#pragma unroll
                    for (int o = 8; o >= 1; o >>= 1) m = fmaxf(m, __shfl_xor(m, o));
                    rr_[mi][q] = m;
                    if (l15 == 0) {
                        int rl = wm * 32 + mi * 16 + hi16 * 4 + q;
                        smax[rl * 2 + wn] = m;
                    }
                }
            __syncthreads();
#pragma unroll
            for (int mi = 0; mi < MF; ++mi)
#pragma unroll
                for (int q = 0; q < 4; ++q) {
                    int rl = wm * 32 + mi * 16 + hi16 * 4 + q;
                    float g = fmaxf(smax[rl * 2], smax[rl * 2 + 1]);
                    float s = 0.0f;
#pragma unroll
                    for (int ni = 0; ni < NF; ++ni) {
                        float e = expf(vvv[mi][ni][q] - g);
                        vvv[mi][ni][q] = e;
                        s += e;
                    }
#pragma unroll
                    for (int o = 8; o >= 1; o >>= 1) s += __shfl_xor(s, o);
                    rr_[mi][q] = s;
                    if (l15 == 0) ssum[rl * 2 + wn] = s;
                }
            __syncthreads();
#pragma unroll
            for (int mi = 0; mi < MF; ++mi)
#pragma unroll
                for (int q = 0; q < 4; ++q) {
                    int rl = wm * 32 + mi * 16 + hi16 * 4 + q;
                    int r  = row0 + rl;
                    if (r >= M) continue;
                    float inv = 1.0f / (ssum[rl * 2] + ssum[rl * 2 + 1]);
#pragma unroll
                    for (int ni = 0; ni < NF; ++ni)
                        Of[(size_t)r * 64 + wn * 32 + ni * 16 + l15] = vvv[mi][ni][q] * inv;
                }
            return;
        } else {
            // legacy: N == 64 cols all in wn==0 fragments (BN==128)
            if (wn == 1) return;
#pragma unroll
            for (int mi = 0; mi < MF; ++mi) {
#pragma unroll
                for (int q = 0; q < 4; ++q) {
                    int r = row0 + wm * WR + mi * 16 + (lane >> 4) * 4 + q;
                    if (r >= M) continue;
                    float v[NF];
                    float mx = -1e30f;
#pragma unroll
                    for (int ni = 0; ni < NF; ++ni) {
                        v[ni] = acc[mi][ni][q] + bias[ni * 16 + l15];
                        mx = fmaxf(mx, v[ni]);
                    }
#pragma unroll
                    for (int o = 8; o >= 1; o >>= 1) mx = fmaxf(mx, __shfl_xor(mx, o));
                    float s = 0.0f;
#pragma unroll
                    for (int ni = 0; ni < NF; ++ni) { v[ni] = expf(v[ni] - mx); s += v[ni]; }
#pragma unroll
                    for (int o = 8; o >= 1; o >>= 1) s += __shfl_xor(s, o);
                    float inv = 1.0f / s;
#pragma unroll
                    for (int ni = 0; ni < NF; ++ni)
                        Of[(size_t)r * 64 + ni * 16 + l15] = v[ni] * inv;
                }
            }
            return;
        }
    }

#pragma unroll
    for (int mi = 0; mi < MF; ++mi) {
#pragma unroll
        for (int q = 0; q < 4; ++q) {
            int r = row0 + wm * WR + mi * 16 + (lane >> 4) * 4 + q;
            if (r >= M) continue;
            float rsv = rs ? rs[r] : 1.0f;
#pragma unroll
            for (int ni = 0; ni < NF; ++ni) {
                int c = col0 + wn * WC + ni * 16 + l15;
                if (c >= N) continue;
                float v = acc[mi][ni][q] * rsv;
                if (bias) v += bias[c];
                if (act == 1) v = fmaxf(v, 0.0f);
                size_t idx = (size_t)r * N + c;
                if (Ob) Ob[idx] = f2b(v);
                if (Of) Of[idx] = v;
            }
        }
    }
}

// ---------------- CSR gather: group-parallel edges, 16B/lane ----------------
// F=256: 2 groups of 32 lanes (2 edges in parallel); F=128: 4 groups of 16 lanes.
// Each lane owns 8 features (16B). Groups combined at end via shfl_xor.
template <int F, int ACTMODE, bool OUTF32>
__global__ __launch_bounds__(256) void gather_bf16(
    const unsigned short* __restrict__ A, unsigned short* __restrict__ Yb,
    float* __restrict__ Yf,
    const int* __restrict__ row_start, const int* __restrict__ csr_src,
    const float* __restrict__ dinv_in, const float* __restrict__ bias)
{
    constexpr int P   = (F == 256) ? 2 : 4;   // parallel edge groups
    constexpr int LPG = 64 / P;               // lanes per group
    const int wave = threadIdx.x >> 6;
    const int lane = threadIdx.x & 63;
    const int node = blockIdx.x * 4 + wave;
    if (node >= NN) return;
    const int g  = lane / LPG;
    const int li = lane % LPG;
    const int f0 = li * 8;

    float acc[8] = {};
    if (g == 0) {
        short8 u = *reinterpret_cast<const short8*>(A + (size_t)node * F + f0);
#pragma unroll
        for (int j = 0; j < 8; ++j) acc[j] = b2f((unsigned short)u[j]);
    }

    const int lo = row_start[node];
    const int hi = row_start[node + 1];
    int e = lo + g;
    for (; e + P < hi; e += 2 * P) {
        int s0 = csr_src[e];
        int s1 = csr_src[e + P];
        short8 u0 = *reinterpret_cast<const short8*>(A + (size_t)s0 * F + f0);
        short8 u1 = *reinterpret_cast<const short8*>(A + (size_t)s1 * F + f0);
#pragma unroll
        for (int j = 0; j < 8; ++j)
            acc[j] += b2f((unsigned short)u0[j]) + b2f((unsigned short)u1[j]);
    }
    if (e < hi) {
        int s0 = csr_src[e];
        short8 u0 = *reinterpret_cast<const short8*>(A + (size_t)s0 * F + f0);
#pragma unroll
        for (int j = 0; j < 8; ++j) acc[j] += b2f((unsigned short)u0[j]);
    }

    // combine groups
#pragma unroll
    for (int j = 0; j < 8; ++j) {
        if (P == 4) acc[j] += __shfl_xor(acc[j], 16);
        acc[j] += __shfl_xor(acc[j], 32);
    }

    const float di = dinv_in[node];
#pragma unroll
    for (int j = 0; j < 8; ++j) {
        float xv = acc[j] * di + bias[f0 + j];
        if (ACTMODE == 1) xv = fmaxf(xv, 0.0f);
        else              xv = 1.0f / (1.0f + expf(-xv)) + 1e-8f;
        acc[j] = xv;
    }
    if (g == 0) {
        if (Yb) {
            short8 o;
#pragma unroll
            for (int j = 0; j < 8; ++j) o[j] = (short)f2b(acc[j]);
            *reinterpret_cast<short8*>(Yb + (size_t)node * F + f0) = o;
        }
        if (OUTF32) {
            float* yf = Yf + (size_t)node * F + f0;
            *reinterpret_cast<float4*>(yf)     = make_float4(acc[0], acc[1], acc[2], acc[3]);
            *reinterpret_cast<float4*>(yf + 4) = make_float4(acc[4], acc[5], acc[6], acc[7]);
        }
    }
}

// ---------------- launcher ----------------
extern "C" void kernel_launch(void* const* d_in, const int* in_sizes, int n_in,
                              void* d_out, int out_size, void* d_ws, size_t ws_size,
                              hipStream_t stream)
{
    const float* x   = (const float*)d_in[0];
    const int*   src = (const int*)d_in[1];
    const int*   dst = (const int*)d_in[2];
    const float* Wg1 = (const float*)d_in[3];
    const float* bg1 = (const float*)d_in[4];
    const float* Wg2 = (const float*)d_in[5];
    const float* bg2 = (const float*)d_in[6];
    const float* Wg3 = (const float*)d_in[7];
    const float* bg3 = (const float*)d_in[8];
    const float* W1  = (const float*)d_in[9];
    const float* b1  = (const float*)d_in[10];
    const float* W2  = (const float*)d_in[11];
    const float* b2  = (const float*)d_in[12];
    const float* W3  = (const float*)d_in[13];
    const float* b3  = (const float*)d_in[14];

    float* out  = (float*)d_out;
    float* prob = out;                     // [N x 64]
    float* gnn  = out + (size_t)NN * ACT;  // [N x 128]

    char* p = (char*)d_ws;
    auto alloc = [&](size_t bytes) { char* r = p; p += (bytes + 255) & ~(size_t)255; return r; };
    float*          dinv_out = (float*)alloc((size_t)NN * 4);
    float*          dinv_in  = (float*)alloc((size_t)NN * 4);
    int*            cnt2     = (int*)alloc((size_t)2 * NN * 4);   // [cnt_in | cnt_out]
    int*            row_st   = (int*)alloc((size_t)(NN + 1) * 4);
    int*            cursor   = (int*)alloc((size_t)NN * 4);
    int*            partial  = (int*)alloc((size_t)SCAN_NB * 4);
    int*            csr_src  = (int*)alloc((size_t)EE * 4);
    unsigned short* xb       = (unsigned short*)alloc((size_t)NN * OBS * 2);
    unsigned short* WT1      = (unsigned short*)alloc((size_t)HID * OBS * 2);
    unsigned short* WT2      = (unsigned short*)alloc((size_t)HID * HID * 2);
    unsigned short* WT3      = (unsigned short*)alloc((size_t)EMB * HID * 2);
    unsigned short* WTm1     = (unsigned short*)alloc((size_t)MLPH * EMB * 2);
    unsigned short* WTm2     = (unsigned short*)alloc((size_t)MLPH * MLPH * 2);
    unsigned short* WTm3     = (unsigned short*)alloc((size_t)ACT * MLPH * 2);
    unsigned short* actA     = (unsigned short*)alloc((size_t)NN * 512 * 2);
    unsigned short* actB     = (unsigned short*)alloc((size_t)NN * 512 * 2);

    int* cnt_in  = cnt2;
    int* cnt_out = cnt2 + NN;

    // --- fused prep: conversions + weight transposes + histogram zeroing ---
    prep_all<<<PREP_ZERO, 256, 0, stream>>>(x, xb, Wg1, Wg2, Wg3, W1, W2, W3,
                                            WT1, WT2, WT3, WTm1, WTm2, WTm3, cnt2);

    // --- degrees + CSR (parallel scan) ---
    const int eb = (EE / 4 + 255) / 256;   // 313 edge blocks
    edge_deg<<<eb, 256, 0, stream>>>(src, dst, cnt_out, cnt_in);
    csr_partials<<<SCAN_NB, 256, 0, stream>>>(cnt_in, cnt_out, partial, dinv_in, dinv_out);
    csr_scan_write<<<SCAN_NB, 256, 0, stream>>>(cnt_in, partial, row_st, cursor);
    fill_csr<<<eb, 256, 0, stream>>>(src, dst, cursor, csr_src);

    const int rb64 = (NN + 63) / 64;      // 313
    const int gb = (NN + 3) / 4;

    // --- GCN layer 1 ---
    gemm_bf16<64, 128, 6><<<rb64 * 2, 256, 0, stream>>>(xb, WT1, NN, OBS, HID, 2, dinv_out, nullptr, 0, actA, nullptr);
    gather_bf16<HID, 1, false><<<gb, 256, 0, stream>>>(actA, actB, nullptr, row_st, csr_src, dinv_in, bg1);

    // --- GCN layer 2 ---
    gemm_bf16<64, 128, 6><<<rb64 * 2, 256, 0, stream>>>(actB, WT2, NN, HID, HID, 2, dinv_out, nullptr, 0, actA, nullptr);
    gather_bf16<HID, 1, false><<<gb, 256, 0, stream>>>(actA, actB, nullptr, row_st, csr_src, dinv_in, bg2);

    // --- GCN layer 3 -> gnn (f32, in d_out) + bf16 copy for MLP ---
    gemm_bf16<64, 64, 6><<<rb64 * 2, 256, 0, stream>>>(actB, WT3, NN, HID, EMB, 2, dinv_out, nullptr, 0, actA, nullptr);
    gather_bf16<EMB, 2, true><<<gb, 256, 0, stream>>>(actA, actB, gnn, row_st, csr_src, dinv_in, bg3);

    // --- MLP (softmax fused into last GEMM, BN=64 cross-wave epilogue) ---
    gemm_bf16<64, 128, 6><<<rb64 * 4, 256, 0, stream>>>(actB, WTm1, NN, EMB, MLPH, 4, nullptr, b1, 1, actA, nullptr);
    gemm_bf16<64, 128, 6><<<rb64 * 4, 256, 0, stream>>>(actA, WTm2, NN, MLPH, MLPH, 4, nullptr, b2, 1, actB, nullptr);
    gemm_bf16<64, 64, 6><<<rb64, 256, 0, stream>>>(actB, WTm3, NN, MLPH, ACT, 1, nullptr, b3, 3, nullptr, prob);
}